// Round 10
// baseline (166.823 us; speedup 1.0000x reference)
//
#include <hip/hip_runtime.h>
#include <math.h>

// N=2048, DH=256, DK=64, FF=32. fp32 in/out, f16 internal.
// ws layout (bytes):
//   q16  @ 0        : 2048x64   f16    (262144)
//   k16  @ 262144   : 2048x64   f16    (262144)
//   vT   @ 524288   : 256x2048  f16    (v transposed)  (1048576)
//   schl @ 1572864  : 2048x2048 f16x2  packed (score_hi, score_lo) (16777216)
//     -> focus (f16) overwrites first half of each schl row in-place;
//        k_feat reads it with row stride 2*NN halves.
// R21 (= R9 + one change). Ledger (clean single-variable pairs only):
//   scores 64^2 @1024        -14
//   feat 16x32->32x64@256    -10   (R3 vs R7; traffic 195->97 MB)
//   mlp chunk prefetch        -3
//   mlp AND-mask               0   (R9 vs R8, noise)
// THIS ROUND: k_feat 32x64@256 -> 64x64@128 (traffic 97->66 MB), same
// per-output MFMA k-chain, same w=1,2,3 reduce order -> bit-identical.

#define NN  2048
#define DHH 256
#define DKK 64

typedef float    f32x4 __attribute__((ext_vector_type(4)));
typedef _Float16 f16x8 __attribute__((ext_vector_type(8)));
typedef _Float16 f16x4 __attribute__((ext_vector_type(4)));
typedef _Float16 f16x2 __attribute__((ext_vector_type(2)));
typedef int      i32x2 __attribute__((ext_vector_type(2)));
typedef int      i32x4 __attribute__((ext_vector_type(4)));

// no __has_builtin guard — returns false on the HOST pass (broke R9)
#define MFMA16(a, b, c) __builtin_amdgcn_mfma_f32_16x16x16f16((a), (b), (c), 0, 0, 0)
#define MFMA32(a, b, c) __builtin_amdgcn_mfma_f32_16x16x32_f16((a), (b), (c), 0, 0, 0)

// pack two f32 (RTZ) then relu on the packed pair (v_cvt_pkrtz + v_pk_max_f16).
// Bit-identical to relu-then-pack: pkrtz(neg) is neg, max(.,0) -> +0.
__device__ __forceinline__ int rp2(float x, float y) {
    f16x2 v = __builtin_bit_cast(f16x2, __builtin_amdgcn_cvt_pkrtz(x, y));
    const f16x2 z = {(_Float16)0, (_Float16)0};
    v = __builtin_elementwise_max(v, z);
    return __builtin_bit_cast(int, v);
}

// ---------------------------------------------------------------------------
// K1: qkv projections (fp32 math). q,k stored f16 row-major; v stored f16
// transposed. grid (32, 6). (R0 LDS body — known good.)
// ---------------------------------------------------------------------------
__global__ __launch_bounds__(256) void k_qkv(
    const float* __restrict__ x,
    const float* __restrict__ Wq, const float* __restrict__ bq,
    const float* __restrict__ Wk, const float* __restrict__ bk,
    const float* __restrict__ Wv, const float* __restrict__ bv,
    _Float16* __restrict__ q16, _Float16* __restrict__ k16,
    _Float16* __restrict__ vT)
{
    __shared__ float As[32][64];
    __shared__ float Bs[32][64];
    __shared__ _Float16 Ts[64 * 72];

    const int t  = threadIdx.x;
    const int m0 = blockIdx.x * 64;
    const int yb = blockIdx.y;

    const float* W; const float* bias; int wld; int cw0;
    if (yb == 0)      { W = Wq; bias = bq; wld = 64;  cw0 = 0; }
    else if (yb == 1) { W = Wk; bias = bk; wld = 64;  cw0 = 0; }
    else              { W = Wv; bias = bv; wld = 256; cw0 = (yb - 2) * 64; }

    const int tx = t & 15, ty = t >> 4;
    float acc[4][4] = {};

    for (int k0 = 0; k0 < DHH; k0 += 32) {
        {
            const int rr = t >> 3;
            const int cc = (t & 7) * 4;
            float4 a0 = *(const float4*)(x + (size_t)(m0 + rr)      * DHH + k0 + cc);
            float4 a1 = *(const float4*)(x + (size_t)(m0 + rr + 32) * DHH + k0 + cc);
            As[cc+0][rr]    = a0.x; As[cc+1][rr]    = a0.y; As[cc+2][rr]    = a0.z; As[cc+3][rr]    = a0.w;
            As[cc+0][rr+32] = a1.x; As[cc+1][rr+32] = a1.y; As[cc+2][rr+32] = a1.z; As[cc+3][rr+32] = a1.w;
        }
        {
            const int bk_ = t >> 4;
            const int bc  = (t & 15) * 4;
            *(float4*)&Bs[bk_][bc]      = *(const float4*)(W + (size_t)(k0 + bk_)      * wld + cw0 + bc);
            *(float4*)&Bs[bk_ + 16][bc] = *(const float4*)(W + (size_t)(k0 + bk_ + 16) * wld + cw0 + bc);
        }
        __syncthreads();
        #pragma unroll
        for (int kk = 0; kk < 32; ++kk) {
            float4 a = *(const float4*)&As[kk][ty * 4];
            float4 b = *(const float4*)&Bs[kk][tx * 4];
            float av[4] = {a.x, a.y, a.z, a.w};
            float bw[4] = {b.x, b.y, b.z, b.w};
            #pragma unroll
            for (int ii = 0; ii < 4; ++ii)
                #pragma unroll
                for (int jj = 0; jj < 4; ++jj)
                    acc[ii][jj] = fmaf(av[ii], bw[jj], acc[ii][jj]);
        }
        __syncthreads();
    }

    float4 b4 = *(const float4*)&bias[cw0 + tx * 4];
    float bc4[4] = {b4.x, b4.y, b4.z, b4.w};

    if (yb < 2) {
        _Float16* outp = (yb == 0) ? q16 : k16;
        #pragma unroll
        for (int ii = 0; ii < 4; ++ii) {
            f16x4 hv;
            #pragma unroll
            for (int jj = 0; jj < 4; ++jj) hv[jj] = (_Float16)(acc[ii][jj] + bc4[jj]);
            *(f16x4*)&outp[(size_t)(m0 + ty * 4 + ii) * 64 + tx * 4] = hv;
        }
    } else {
        #pragma unroll
        for (int jj = 0; jj < 4; ++jj) {
            f16x4 hv;
            #pragma unroll
            for (int ii = 0; ii < 4; ++ii) hv[ii] = (_Float16)(acc[ii][jj] + bc4[jj]);
            *(f16x4*)&Ts[(tx * 4 + jj) * 72 + ty * 4] = hv;
        }
        __syncthreads();
        {
            const int c = t >> 2, seg = t & 3;
            f16x8 r0 = *(const f16x8*)&Ts[c * 72 + seg * 16];
            f16x8 r1 = *(const f16x8*)&Ts[c * 72 + seg * 16 + 8];
            *(f16x8*)&vT[(size_t)(cw0 + c) * NN + m0 + seg * 16]     = r0;
            *(f16x8*)&vT[(size_t)(cw0 + c) * NN + m0 + seg * 16 + 8] = r1;
        }
    }
}

// ---------------------------------------------------------------------------
// K2: scores = k16 @ q16^T via f16 MFMA (dense). Packed (hi, lo) f16x2 out.
// 64x64 tile, 4 waves (wave w owns j-cols [w*16, w*16+16)), grid (32,32) =
// 1024 blocks -> 16 waves/CU. Per-output math identical to the 128x128
// version: two chained K=32 MFMA32s, same operand order.
// ---------------------------------------------------------------------------
__global__ __launch_bounds__(256) void k_scores(
    const _Float16* __restrict__ q16, const _Float16* __restrict__ k16,
    f16x2* __restrict__ schl)
{
    const int t    = threadIdx.x;
    const int lane = t & 63;
    const int w    = t >> 6;
    const int col  = lane & 15;
    const int q    = lane >> 4;

    const int i0 = blockIdx.y * 64;
    const int j0 = blockIdx.x * 64 + w * 16;

    f32x4 acc[4] = {};

    #pragma unroll
    for (int ks = 0; ks < 2; ++ks) {
        f16x8 a[4], b;
        #pragma unroll
        for (int f = 0; f < 4; ++f)
            a[f] = *(const f16x8*)&k16[(size_t)(i0 + f * 16 + col) * 64 + ks * 32 + q * 8];
        b = *(const f16x8*)&q16[(size_t)(j0 + col) * 64 + ks * 32 + q * 8];
        #pragma unroll
        for (int fm = 0; fm < 4; ++fm)
            acc[fm] = MFMA32(a[fm], b, acc[fm]);
    }

    #pragma unroll
    for (int fm = 0; fm < 4; ++fm)
        #pragma unroll
        for (int r = 0; r < 4; ++r) {
            const size_t idx = (size_t)(i0 + fm * 16 + q * 4 + r) * NN + j0 + col;
            const float val = acc[fm][r];
            const _Float16 h = (_Float16)val;
            f16x2 pk; pk[0] = h; pk[1] = (_Float16)(val - (float)h);
            schl[idx] = pk;
        }
}

// ---------------------------------------------------------------------------
// K3: per-edge MLP + row softmax. R8 body (chunk prefetch) + AND-mask B1
// build (bit-identical truth table to the R0 ternaries). Unchanged vs R9.
// ---------------------------------------------------------------------------
__global__ __launch_bounds__(256) void k_mlp(
    const f16x2* __restrict__ schl,
    const float* __restrict__ adj, const float* __restrict__ dense,
    const float* __restrict__ W1, const float* __restrict__ b1,
    const float* __restrict__ W2, const float* __restrict__ b2,
    const float* __restrict__ W3,
    _Float16* __restrict__ focus)   // row stride 2*NN halves (overlays schl)
{
    __shared__ float red[8];

    const int t    = threadIdx.x;
    const int lane = t & 63;
    const int w    = t >> 6;
    const int col  = lane & 15;
    const int q    = lane >> 4;
    const int i    = blockIdx.x;

    // ---- layer-1 A frags (k=4q+j): q0 {W0hi,W0hi,W1_1,W1_2}, q1 k4=W0lo ----
    f16x4 l1A0 = {}, l1A1 = {};
    {
        const float w0a = W1[col], w0b = W1[col + 16];
        const _Float16 h0a = (_Float16)w0a, h0b = (_Float16)w0b;
        if (q == 0) {
            l1A0[0] = h0a; l1A0[1] = h0a;
            l1A0[2] = (_Float16)W1[32 + col];
            l1A0[3] = (_Float16)W1[64 + col];
            l1A1[0] = h0b; l1A1[1] = h0b;
            l1A1[2] = (_Float16)W1[32 + col + 16];
            l1A1[3] = (_Float16)W1[64 + col + 16];
        } else if (q == 1) {
            l1A0[0] = (_Float16)(w0a - (float)h0a);
            l1A1[0] = (_Float16)(w0b - (float)h0b);
        }
    }

    // ---- per-lane B1 masks (same truth table as the R0 ternaries) ----
    const int mask0 = (q == 0) ? -1 : ((q == 1) ? 0xFFFF : 0);
    const int mask1 = (q == 0) ? -1 : 0;

    // ---- layer-2 A frags: w2A[fh][oh][j] = W2[fh*16 + 4q+j][oh*16 + col] ----
    f16x4 w2A[2][2];
    #pragma unroll
    for (int fh = 0; fh < 2; ++fh)
        #pragma unroll
        for (int oh = 0; oh < 2; ++oh)
            #pragma unroll
            for (int j = 0; j < 4; ++j)
                w2A[fh][oh][j] = (_Float16)W2[(fh * 16 + q * 4 + j) * 32 + oh * 16 + col];

    // ---- layer-3 A frags (W3 broadcast over m) ----
    f16x4 a3lo, a3hi;
    #pragma unroll
    for (int j = 0; j < 4; ++j) {
        a3lo[j] = (_Float16)W3[q * 4 + j];
        a3hi[j] = (_Float16)W3[16 + q * 4 + j];
    }

    // ---- biases (indexed by feat/out = q*4+r) ----
    f32x4 c1a, c1b, c2a, c2b;
    #pragma unroll
    for (int r = 0; r < 4; ++r) {
        c1a[r] = b1[q * 4 + r];
        c1b[r] = b1[16 + q * 4 + r];
        c2a[r] = b2[q * 4 + r];
        c2b[r] = b2[16 + q * 4 + r];
    }

    const f16x2* srow = schl  + (size_t)i * NN;
    const float* arow = adj   + (size_t)i * NN;
    const float* drow = dense + (size_t)i * NN;

    const f32x4 zero4 = {0.f, 0.f, 0.f, 0.f};
    float lg[8];

    // ---- prefetch chunk 0 ----
    i32x4  sv = *(const i32x4*)&srow[w * 512 + col * 4];
    float4 av = *(const float4*)&arow[w * 512 + col * 4];
    float4 dv = *(const float4*)&drow[w * 512 + col * 4];

    for (int c = 0; c < 8; ++c) {
        const i32x4  svc = sv;
        const float4 avc = av;
        const float4 dvc = dv;
        if (c < 7) {
            const int ebn = w * 512 + (c + 1) * 64 + col * 4;
            sv = *(const i32x4*)&srow[ebn];
            av = *(const float4*)&arow[ebn];
            dv = *(const float4*)&drow[ebn];
        }
        const float aa[4] = {avc.x, avc.y, avc.z, avc.w};
        const float dd[4] = {dvc.x, dvc.y, dvc.z, dvc.w};

        float lgc = 0.f;
        #pragma unroll
        for (int st = 0; st < 4; ++st) {
            const int d0 = svc[st];
            const int d1 = __builtin_bit_cast(int,
                __builtin_amdgcn_cvt_pkrtz(aa[st], dd[st]));

            i32x2 b1v = {d0 & mask0, d1 & mask1};
            f16x4 B1 = __builtin_bit_cast(f16x4, b1v);

            // ---- layer 1 ----
            f32x4 hpA = MFMA16(l1A0, B1, c1a);
            f32x4 hpB = MFMA16(l1A1, B1, c1b);

            i32x2 p0 = { rp2(hpA[0], hpA[1]), rp2(hpA[2], hpA[3]) };
            i32x2 p1 = { rp2(hpB[0], hpB[1]), rp2(hpB[2], hpB[3]) };
            f16x4 B2f0 = __builtin_bit_cast(f16x4, p0);   // feats 0..15
            f16x4 B2f1 = __builtin_bit_cast(f16x4, p1);   // feats 16..31

            // ---- layer 2 (K-split chained) ----
            f32x4 acc0 = MFMA16(w2A[0][0], B2f0, c2a);
            acc0 = MFMA16(w2A[1][0], B2f1, acc0);
            f32x4 acc1 = MFMA16(w2A[0][1], B2f0, c2b);
            acc1 = MFMA16(w2A[1][1], B2f1, acc1);

            i32x2 p3a = { rp2(acc0[0], acc0[1]), rp2(acc0[2], acc0[3]) };
            i32x2 p3b = { rp2(acc1[0], acc1[1]), rp2(acc1[2], acc1[3]) };
            f16x4 B3f0 = __builtin_bit_cast(f16x4, p3a);
            f16x4 B3f1 = __builtin_bit_cast(f16x4, p3b);

            // ---- layer 3: logit in every lane (C3 rows identical) ----
            f32x4 c3 = MFMA16(a3lo, B3f0, zero4);
            c3 = MFMA16(a3hi, B3f1, c3);
            lgc = (q == st) ? c3[0] : lgc;   // lane (q,col): edge base+4*col+q
        }
        lg[c] = lgc;
    }

    // ---- row softmax (edge = w*512 + c*64 + 4*col + q) ----
    float lmax = -1e30f;
    #pragma unroll
    for (int u = 0; u < 8; ++u) lmax = fmaxf(lmax, lg[u]);
    #pragma unroll
    for (int off = 32; off > 0; off >>= 1)
        lmax = fmaxf(lmax, __shfl_xor(lmax, off, 64));
    if (lane == 0) red[w] = lmax;
    __syncthreads();
    const float rmax = fmaxf(fmaxf(red[0], red[1]), fmaxf(red[2], red[3]));

    float lsum = 0.f;
    #pragma unroll
    for (int u = 0; u < 8; ++u) { lg[u] = __expf(lg[u] - rmax); lsum += lg[u]; }
    #pragma unroll
    for (int off = 32; off > 0; off >>= 1)
        lsum += __shfl_xor(lsum, off, 64);
    if (lane == 0) red[4 + w] = lsum;
    __syncthreads();
    const float inv = 1.f / (red[4] + red[5] + red[6] + red[7]);

    _Float16* hrow = focus + (size_t)i * 2 * NN;
    const int eb = w * 512 + 4 * col + q;
    #pragma unroll
    for (int u = 0; u < 8; ++u)
        hrow[eb + u * 64] = (_Float16)(lg[u] * inv);
}

// ---------------------------------------------------------------------------
// K4: feature = focus @ v via f16 MFMA, K split 4-way across waves + LDS
// reduce. R21: 64x64 output tile per block, grid (4,32) = 128 blocks
// (traffic 97->66 MB; extends the measured winning direction 16x32->32x64
// = -10us). Per-output chain (16 MFMA32s in k-order) and w=1,2,3 reduce
// order unchanged -> bit-identical. focus row stride = 2*NN halves.
// ---------------------------------------------------------------------------
__global__ __launch_bounds__(256) void k_feat(
    const _Float16* __restrict__ focus, const _Float16* __restrict__ vT,
    float* __restrict__ out)
{
    __shared__ float rbuf[3][64][68];   // 64 floats/lane + 4 pad

    const int t    = threadIdx.x;
    const int lane = t & 63;
    const int w    = t >> 6;
    const int col  = lane & 15;
    const int q    = lane >> 4;

    const int m0 = blockIdx.y * 64;
    const int n0 = blockIdx.x * 64;

    f32x4 acc[4][4] = {};

    size_t arow[4];
    #pragma unroll
    for (int mi = 0; mi < 4; ++mi)
        arow[mi] = (size_t)(m0 + mi * 16 + col) * (2 * NN);
    const int kb = w * 512 + q * 8;

    #pragma unroll 2
    for (int k0 = 0; k0 < 512; k0 += 32) {
        const int ko = kb + k0;
        f16x8 a[4], b[4];
        #pragma unroll
        for (int mi = 0; mi < 4; ++mi)
            a[mi] = *(const f16x8*)&focus[arow[mi] + ko];
        #pragma unroll
        for (int ni = 0; ni < 4; ++ni)
            b[ni] = *(const f16x8*)&vT[(size_t)(n0 + ni * 16 + col) * NN + ko];
        #pragma unroll
        for (int mi = 0; mi < 4; ++mi)
            #pragma unroll
            for (int ni = 0; ni < 4; ++ni)
                acc[mi][ni] = MFMA32(a[mi], b[ni], acc[mi][ni]);
    }

    if (w != 0) {
        #pragma unroll
        for (int mi = 0; mi < 4; ++mi)
            #pragma unroll
            for (int ni = 0; ni < 4; ++ni)
                *(float4*)&rbuf[w - 1][lane][mi * 16 + ni * 4] = *(float4*)&acc[mi][ni];
    }
    __syncthreads();

    if (w == 0) {
        #pragma unroll
        for (int j = 0; j < 3; ++j)
            #pragma unroll
            for (int mi = 0; mi < 4; ++mi)
                #pragma unroll
                for (int ni = 0; ni < 4; ++ni) {
                    float4 p = *(const float4*)&rbuf[j][lane][mi * 16 + ni * 4];
                    acc[mi][ni][0] += p.x; acc[mi][ni][1] += p.y;
                    acc[mi][ni][2] += p.z; acc[mi][ni][3] += p.w;
                }
        #pragma unroll
        for (int mi = 0; mi < 4; ++mi)
            #pragma unroll
            for (int ni = 0; ni < 4; ++ni)
                #pragma unroll
                for (int r = 0; r < 4; ++r)
                    out[(size_t)(m0 + mi * 16 + q * 4 + r) * DHH + n0 + ni * 16 + col]
                        = acc[mi][ni][r];
    }
}

// ---------------------------------------------------------------------------
extern "C" void kernel_launch(void* const* d_in, const int* in_sizes, int n_in,
                              void* d_out, int out_size, void* d_ws, size_t ws_size,
                              hipStream_t stream) {
    const float* x     = (const float*)d_in[0];
    const float* adj   = (const float*)d_in[1];
    const float* dense = (const float*)d_in[2];
    const float* Wq    = (const float*)d_in[3];
    const float* bq    = (const float*)d_in[4];
    const float* Wk    = (const float*)d_in[5];
    const float* bk    = (const float*)d_in[6];
    const float* Wv    = (const float*)d_in[7];
    const float* bv    = (const float*)d_in[8];
    const float* W1    = (const float*)d_in[9];
    const float* b1    = (const float*)d_in[10];
    const float* W2    = (const float*)d_in[11];
    const float* b2    = (const float*)d_in[12];
    const float* W3    = (const float*)d_in[13];
    float* out = (float*)d_out;

    char* wsb = (char*)d_ws;
    _Float16* q16   = (_Float16*)(wsb);
    _Float16* k16   = (_Float16*)(wsb + 262144);
    _Float16* vT    = (_Float16*)(wsb + 524288);
    f16x2*    schl  = (f16x2*)   (wsb + 1572864);
    _Float16* focus = (_Float16*)(wsb + 1572864);   // row stride 2*NN, in-place

    hipLaunchKernelGGL(k_qkv,    dim3(32, 6),  dim3(256), 0, stream,
                       x, Wq, bq, Wk, bk, Wv, bv, q16, k16, vT);
    hipLaunchKernelGGL(k_scores, dim3(32, 32), dim3(256), 0, stream, q16, k16, schl);
    hipLaunchKernelGGL(k_mlp,    dim3(2048),   dim3(256), 0, stream,
                       schl, adj, dense, W1, b1, W2, b2, W3, focus);
    hipLaunchKernelGGL(k_feat,   dim3(4, 32),  dim3(256), 0, stream,
                       focus, vT, out);
}

// Round 11
// 160.711 us; speedup vs baseline: 1.0380x; 1.0380x over previous
//
#include <hip/hip_runtime.h>
#include <math.h>

// N=2048, DH=256, DK=64, FF=32. fp32 in/out, f16 internal.
// ws layout (bytes):
//   q16  @ 0        : 2048x64   f16    (262144)
//   k16  @ 262144   : 2048x64   f16    (262144)
//   vT   @ 524288   : 256x2048  f16    (v transposed)  (1048576)
//   schl @ 1572864  : 2048x2048 f16x2  packed (score_hi, score_lo) (16777216)
//     -> focus (f16) overwrites first half of each schl row in-place;
//        k_feat reads it with row stride 2*NN halves.
// R22 (= R8 best-measured 162.5us + ONE change). Ledger (clean pairs):
//   scores 64^2 @1024        -14
//   feat 16x32->32x64@256    -10   (32x64@256 = sweet spot; 64x64@128 = +4)
//   mlp chunk prefetch        -3
//   mlp AND-mask               0
// THIS ROUND: k_feat XCD-chunked tile remap (bijective, 256%8==0): blocks
// sharing a focus m-tile land on the SAME XCD -> focus fetched once per XCD
// L2 and reused 4x (L3 traffic ~97 -> ~16 MB) at unchanged 1 block/CU
// occupancy. Pure blockIdx->tile remap; math bit-identical.

#define NN  2048
#define DHH 256
#define DKK 64

typedef float    f32x4 __attribute__((ext_vector_type(4)));
typedef _Float16 f16x8 __attribute__((ext_vector_type(8)));
typedef _Float16 f16x4 __attribute__((ext_vector_type(4)));
typedef _Float16 f16x2 __attribute__((ext_vector_type(2)));
typedef int      i32x2 __attribute__((ext_vector_type(2)));
typedef int      i32x4 __attribute__((ext_vector_type(4)));

// no __has_builtin guard — returns false on the HOST pass (broke R9)
#define MFMA16(a, b, c) __builtin_amdgcn_mfma_f32_16x16x16f16((a), (b), (c), 0, 0, 0)
#define MFMA32(a, b, c) __builtin_amdgcn_mfma_f32_16x16x32_f16((a), (b), (c), 0, 0, 0)

// pack two f32 (RTZ) then relu on the packed pair (v_cvt_pkrtz + v_pk_max_f16).
// Bit-identical to relu-then-pack: pkrtz(neg) is neg, max(.,0) -> +0.
__device__ __forceinline__ int rp2(float x, float y) {
    f16x2 v = __builtin_bit_cast(f16x2, __builtin_amdgcn_cvt_pkrtz(x, y));
    const f16x2 z = {(_Float16)0, (_Float16)0};
    v = __builtin_elementwise_max(v, z);
    return __builtin_bit_cast(int, v);
}

// ---------------------------------------------------------------------------
// K1: qkv projections (fp32 math). q,k stored f16 row-major; v stored f16
// transposed. grid (32, 6). (R0 LDS body — known good.)
// ---------------------------------------------------------------------------
__global__ __launch_bounds__(256) void k_qkv(
    const float* __restrict__ x,
    const float* __restrict__ Wq, const float* __restrict__ bq,
    const float* __restrict__ Wk, const float* __restrict__ bk,
    const float* __restrict__ Wv, const float* __restrict__ bv,
    _Float16* __restrict__ q16, _Float16* __restrict__ k16,
    _Float16* __restrict__ vT)
{
    __shared__ float As[32][64];
    __shared__ float Bs[32][64];
    __shared__ _Float16 Ts[64 * 72];

    const int t  = threadIdx.x;
    const int m0 = blockIdx.x * 64;
    const int yb = blockIdx.y;

    const float* W; const float* bias; int wld; int cw0;
    if (yb == 0)      { W = Wq; bias = bq; wld = 64;  cw0 = 0; }
    else if (yb == 1) { W = Wk; bias = bk; wld = 64;  cw0 = 0; }
    else              { W = Wv; bias = bv; wld = 256; cw0 = (yb - 2) * 64; }

    const int tx = t & 15, ty = t >> 4;
    float acc[4][4] = {};

    for (int k0 = 0; k0 < DHH; k0 += 32) {
        {
            const int rr = t >> 3;
            const int cc = (t & 7) * 4;
            float4 a0 = *(const float4*)(x + (size_t)(m0 + rr)      * DHH + k0 + cc);
            float4 a1 = *(const float4*)(x + (size_t)(m0 + rr + 32) * DHH + k0 + cc);
            As[cc+0][rr]    = a0.x; As[cc+1][rr]    = a0.y; As[cc+2][rr]    = a0.z; As[cc+3][rr]    = a0.w;
            As[cc+0][rr+32] = a1.x; As[cc+1][rr+32] = a1.y; As[cc+2][rr+32] = a1.z; As[cc+3][rr+32] = a1.w;
        }
        {
            const int bk_ = t >> 4;
            const int bc  = (t & 15) * 4;
            *(float4*)&Bs[bk_][bc]      = *(const float4*)(W + (size_t)(k0 + bk_)      * wld + cw0 + bc);
            *(float4*)&Bs[bk_ + 16][bc] = *(const float4*)(W + (size_t)(k0 + bk_ + 16) * wld + cw0 + bc);
        }
        __syncthreads();
        #pragma unroll
        for (int kk = 0; kk < 32; ++kk) {
            float4 a = *(const float4*)&As[kk][ty * 4];
            float4 b = *(const float4*)&Bs[kk][tx * 4];
            float av[4] = {a.x, a.y, a.z, a.w};
            float bw[4] = {b.x, b.y, b.z, b.w};
            #pragma unroll
            for (int ii = 0; ii < 4; ++ii)
                #pragma unroll
                for (int jj = 0; jj < 4; ++jj)
                    acc[ii][jj] = fmaf(av[ii], bw[jj], acc[ii][jj]);
        }
        __syncthreads();
    }

    float4 b4 = *(const float4*)&bias[cw0 + tx * 4];
    float bc4[4] = {b4.x, b4.y, b4.z, b4.w};

    if (yb < 2) {
        _Float16* outp = (yb == 0) ? q16 : k16;
        #pragma unroll
        for (int ii = 0; ii < 4; ++ii) {
            f16x4 hv;
            #pragma unroll
            for (int jj = 0; jj < 4; ++jj) hv[jj] = (_Float16)(acc[ii][jj] + bc4[jj]);
            *(f16x4*)&outp[(size_t)(m0 + ty * 4 + ii) * 64 + tx * 4] = hv;
        }
    } else {
        #pragma unroll
        for (int jj = 0; jj < 4; ++jj) {
            f16x4 hv;
            #pragma unroll
            for (int ii = 0; ii < 4; ++ii) hv[ii] = (_Float16)(acc[ii][jj] + bc4[jj]);
            *(f16x4*)&Ts[(tx * 4 + jj) * 72 + ty * 4] = hv;
        }
        __syncthreads();
        {
            const int c = t >> 2, seg = t & 3;
            f16x8 r0 = *(const f16x8*)&Ts[c * 72 + seg * 16];
            f16x8 r1 = *(const f16x8*)&Ts[c * 72 + seg * 16 + 8];
            *(f16x8*)&vT[(size_t)(cw0 + c) * NN + m0 + seg * 16]     = r0;
            *(f16x8*)&vT[(size_t)(cw0 + c) * NN + m0 + seg * 16 + 8] = r1;
        }
    }
}

// ---------------------------------------------------------------------------
// K2: scores = k16 @ q16^T via f16 MFMA (dense). Packed (hi, lo) f16x2 out.
// 64x64 tile, 4 waves (wave w owns j-cols [w*16, w*16+16)), grid (32,32) =
// 1024 blocks -> 16 waves/CU. Per-output math identical to the 128x128
// version: two chained K=32 MFMA32s, same operand order.
// ---------------------------------------------------------------------------
__global__ __launch_bounds__(256) void k_scores(
    const _Float16* __restrict__ q16, const _Float16* __restrict__ k16,
    f16x2* __restrict__ schl)
{
    const int t    = threadIdx.x;
    const int lane = t & 63;
    const int w    = t >> 6;
    const int col  = lane & 15;
    const int q    = lane >> 4;

    const int i0 = blockIdx.y * 64;
    const int j0 = blockIdx.x * 64 + w * 16;

    f32x4 acc[4] = {};

    #pragma unroll
    for (int ks = 0; ks < 2; ++ks) {
        f16x8 a[4], b;
        #pragma unroll
        for (int f = 0; f < 4; ++f)
            a[f] = *(const f16x8*)&k16[(size_t)(i0 + f * 16 + col) * 64 + ks * 32 + q * 8];
        b = *(const f16x8*)&q16[(size_t)(j0 + col) * 64 + ks * 32 + q * 8];
        #pragma unroll
        for (int fm = 0; fm < 4; ++fm)
            acc[fm] = MFMA32(a[fm], b, acc[fm]);
    }

    #pragma unroll
    for (int fm = 0; fm < 4; ++fm)
        #pragma unroll
        for (int r = 0; r < 4; ++r) {
            const size_t idx = (size_t)(i0 + fm * 16 + q * 4 + r) * NN + j0 + col;
            const float val = acc[fm][r];
            const _Float16 h = (_Float16)val;
            f16x2 pk; pk[0] = h; pk[1] = (_Float16)(val - (float)h);
            schl[idx] = pk;
        }
}

// ---------------------------------------------------------------------------
// K3: per-edge MLP + row softmax. R8 body: R0 serial-st chain + 1-chunk-deep
// prefetch of sv/av/dv (the loads move, the st loop is byte-identical to R0).
// ---------------------------------------------------------------------------
__global__ __launch_bounds__(256) void k_mlp(
    const f16x2* __restrict__ schl,
    const float* __restrict__ adj, const float* __restrict__ dense,
    const float* __restrict__ W1, const float* __restrict__ b1,
    const float* __restrict__ W2, const float* __restrict__ b2,
    const float* __restrict__ W3,
    _Float16* __restrict__ focus)   // row stride 2*NN halves (overlays schl)
{
    __shared__ float red[8];

    const int t    = threadIdx.x;
    const int lane = t & 63;
    const int w    = t >> 6;
    const int col  = lane & 15;
    const int q    = lane >> 4;
    const int i    = blockIdx.x;

    // ---- layer-1 A frags (k=4q+j): q0 {W0hi,W0hi,W1_1,W1_2}, q1 k4=W0lo ----
    f16x4 l1A0 = {}, l1A1 = {};
    {
        const float w0a = W1[col], w0b = W1[col + 16];
        const _Float16 h0a = (_Float16)w0a, h0b = (_Float16)w0b;
        if (q == 0) {
            l1A0[0] = h0a; l1A0[1] = h0a;
            l1A0[2] = (_Float16)W1[32 + col];
            l1A0[3] = (_Float16)W1[64 + col];
            l1A1[0] = h0b; l1A1[1] = h0b;
            l1A1[2] = (_Float16)W1[32 + col + 16];
            l1A1[3] = (_Float16)W1[64 + col + 16];
        } else if (q == 1) {
            l1A0[0] = (_Float16)(w0a - (float)h0a);
            l1A1[0] = (_Float16)(w0b - (float)h0b);
        }
    }

    // ---- layer-2 A frags: w2A[fh][oh][j] = W2[fh*16 + 4q+j][oh*16 + col] ----
    f16x4 w2A[2][2];
    #pragma unroll
    for (int fh = 0; fh < 2; ++fh)
        #pragma unroll
        for (int oh = 0; oh < 2; ++oh)
            #pragma unroll
            for (int j = 0; j < 4; ++j)
                w2A[fh][oh][j] = (_Float16)W2[(fh * 16 + q * 4 + j) * 32 + oh * 16 + col];

    // ---- layer-3 A frags (W3 broadcast over m) ----
    f16x4 a3lo, a3hi;
    #pragma unroll
    for (int j = 0; j < 4; ++j) {
        a3lo[j] = (_Float16)W3[q * 4 + j];
        a3hi[j] = (_Float16)W3[16 + q * 4 + j];
    }

    // ---- biases (indexed by feat/out = q*4+r) ----
    f32x4 c1a, c1b, c2a, c2b;
    #pragma unroll
    for (int r = 0; r < 4; ++r) {
        c1a[r] = b1[q * 4 + r];
        c1b[r] = b1[16 + q * 4 + r];
        c2a[r] = b2[q * 4 + r];
        c2b[r] = b2[16 + q * 4 + r];
    }

    const f16x2* srow = schl  + (size_t)i * NN;
    const float* arow = adj   + (size_t)i * NN;
    const float* drow = dense + (size_t)i * NN;

    const f32x4 zero4 = {0.f, 0.f, 0.f, 0.f};
    float lg[8];

    // ---- prefetch chunk 0 ----
    i32x4  sv = *(const i32x4*)&srow[w * 512 + col * 4];
    float4 av = *(const float4*)&arow[w * 512 + col * 4];
    float4 dv = *(const float4*)&drow[w * 512 + col * 4];

    for (int c = 0; c < 8; ++c) {
        const i32x4  svc = sv;
        const float4 avc = av;
        const float4 dvc = dv;
        if (c < 7) {
            const int ebn = w * 512 + (c + 1) * 64 + col * 4;
            sv = *(const i32x4*)&srow[ebn];
            av = *(const float4*)&arow[ebn];
            dv = *(const float4*)&drow[ebn];
        }
        const float aa[4] = {avc.x, avc.y, avc.z, avc.w};
        const float dd[4] = {dvc.x, dvc.y, dvc.z, dvc.w};

        float lgc = 0.f;
        #pragma unroll
        for (int st = 0; st < 4; ++st) {
            const int d0 = svc[st];
            const int d1 = __builtin_bit_cast(int,
                __builtin_amdgcn_cvt_pkrtz(aa[st], dd[st]));

            const int m0 = (q == 0) ? d0 : ((q == 1) ? (d0 & 0xFFFF) : 0);
            const int m1 = (q == 0) ? d1 : 0;
            i32x2 b1v = {m0, m1};
            f16x4 B1 = __builtin_bit_cast(f16x4, b1v);

            // ---- layer 1 ----
            f32x4 hpA = MFMA16(l1A0, B1, c1a);
            f32x4 hpB = MFMA16(l1A1, B1, c1b);

            i32x2 p0 = { rp2(hpA[0], hpA[1]), rp2(hpA[2], hpA[3]) };
            i32x2 p1 = { rp2(hpB[0], hpB[1]), rp2(hpB[2], hpB[3]) };
            f16x4 B2f0 = __builtin_bit_cast(f16x4, p0);   // feats 0..15
            f16x4 B2f1 = __builtin_bit_cast(f16x4, p1);   // feats 16..31

            // ---- layer 2 (K-split chained) ----
            f32x4 acc0 = MFMA16(w2A[0][0], B2f0, c2a);
            acc0 = MFMA16(w2A[1][0], B2f1, acc0);
            f32x4 acc1 = MFMA16(w2A[0][1], B2f0, c2b);
            acc1 = MFMA16(w2A[1][1], B2f1, acc1);

            i32x2 p3a = { rp2(acc0[0], acc0[1]), rp2(acc0[2], acc0[3]) };
            i32x2 p3b = { rp2(acc1[0], acc1[1]), rp2(acc1[2], acc1[3]) };
            f16x4 B3f0 = __builtin_bit_cast(f16x4, p3a);
            f16x4 B3f1 = __builtin_bit_cast(f16x4, p3b);

            // ---- layer 3: logit in every lane (C3 rows identical) ----
            f32x4 c3 = MFMA16(a3lo, B3f0, zero4);
            c3 = MFMA16(a3hi, B3f1, c3);
            lgc = (q == st) ? c3[0] : lgc;   // lane (q,col): edge base+4*col+q
        }
        lg[c] = lgc;
    }

    // ---- row softmax (edge = w*512 + c*64 + 4*col + q) ----
    float lmax = -1e30f;
    #pragma unroll
    for (int u = 0; u < 8; ++u) lmax = fmaxf(lmax, lg[u]);
    #pragma unroll
    for (int off = 32; off > 0; off >>= 1)
        lmax = fmaxf(lmax, __shfl_xor(lmax, off, 64));
    if (lane == 0) red[w] = lmax;
    __syncthreads();
    const float rmax = fmaxf(fmaxf(red[0], red[1]), fmaxf(red[2], red[3]));

    float lsum = 0.f;
    #pragma unroll
    for (int u = 0; u < 8; ++u) { lg[u] = __expf(lg[u] - rmax); lsum += lg[u]; }
    #pragma unroll
    for (int off = 32; off > 0; off >>= 1)
        lsum += __shfl_xor(lsum, off, 64);
    if (lane == 0) red[4 + w] = lsum;
    __syncthreads();
    const float inv = 1.f / (red[4] + red[5] + red[6] + red[7]);

    _Float16* hrow = focus + (size_t)i * 2 * NN;
    const int eb = w * 512 + 4 * col + q;
    #pragma unroll
    for (int u = 0; u < 8; ++u)
        hrow[eb + u * 64] = (_Float16)(lg[u] * inv);
}

// ---------------------------------------------------------------------------
// K4: feature = focus @ v via f16 MFMA, K split 4-way across waves + LDS
// reduce. 32x64 output tile per block, grid (4,64) = 256 blocks (measured
// sweet spot). R22: XCD-chunked tile remap — lid = x + 4*y (dispatch id);
// xcd = lid&7 (round-robin assumption); XCD c owns m-tiles c*8..c*8+7 for
// all 4 n-tiles, so its L2 fetches each focus m-tile once and reuses it 4x.
// Bijective (256 blocks, 8 | 256). Math is a pure function of (m0,n0) ->
// bit-identical. focus row stride = 2*NN halves (overlaid on schl).
// ---------------------------------------------------------------------------
__global__ __launch_bounds__(256) void k_feat(
    const _Float16* __restrict__ focus, const _Float16* __restrict__ vT,
    float* __restrict__ out)
{
    __shared__ float rbuf[3][64][36];   // pad 32->36: 8-way (not 16-way) conflict

    const int t    = threadIdx.x;
    const int lane = t & 63;
    const int w    = t >> 6;
    const int col  = lane & 15;
    const int q    = lane >> 4;

    // ---- XCD-chunked bijective remap of the 256-block grid ----
    const int lid = blockIdx.x + blockIdx.y * 4;   // dispatch-linear id
    const int xcd = lid & 7;
    const int s   = lid >> 3;                      // 0..31 within XCD
    const int m0  = (xcd * 8 + (s >> 2)) * 32;     // m-tile 0..63
    const int n0  = (s & 3) * 64;                  // n-tile 0..3

    f32x4 acc[2][4] = {};

    const size_t arow0 = (size_t)(m0 + col) * (2 * NN);
    const size_t arow1 = (size_t)(m0 + 16 + col) * (2 * NN);
    const int kb = w * 512 + q * 8;

    #pragma unroll 4
    for (int k0 = 0; k0 < 512; k0 += 32) {
        const int ko = kb + k0;
        f16x8 a0 = *(const f16x8*)&focus[arow0 + ko];
        f16x8 a1 = *(const f16x8*)&focus[arow1 + ko];
        f16x8 b[4];
        #pragma unroll
        for (int ni = 0; ni < 4; ++ni)
            b[ni] = *(const f16x8*)&vT[(size_t)(n0 + ni * 16 + col) * NN + ko];
        #pragma unroll
        for (int ni = 0; ni < 4; ++ni) {
            acc[0][ni] = MFMA32(a0, b[ni], acc[0][ni]);
            acc[1][ni] = MFMA32(a1, b[ni], acc[1][ni]);
        }
    }

    if (w != 0) {
        #pragma unroll
        for (int mi = 0; mi < 2; ++mi)
            #pragma unroll
            for (int ni = 0; ni < 4; ++ni)
                *(float4*)&rbuf[w - 1][lane][mi * 16 + ni * 4] = *(float4*)&acc[mi][ni];
    }
    __syncthreads();

    if (w == 0) {
        #pragma unroll
        for (int j = 0; j < 3; ++j)
            #pragma unroll
            for (int mi = 0; mi < 2; ++mi)
                #pragma unroll
                for (int ni = 0; ni < 4; ++ni) {
                    float4 p = *(const float4*)&rbuf[j][lane][mi * 16 + ni * 4];
                    acc[mi][ni][0] += p.x; acc[mi][ni][1] += p.y;
                    acc[mi][ni][2] += p.z; acc[mi][ni][3] += p.w;
                }
        #pragma unroll
        for (int mi = 0; mi < 2; ++mi)
            #pragma unroll
            for (int ni = 0; ni < 4; ++ni)
                #pragma unroll
                for (int r = 0; r < 4; ++r)
                    out[(size_t)(m0 + mi * 16 + q * 4 + r) * DHH + n0 + ni * 16 + col]
                        = acc[mi][ni][r];
    }
}

// ---------------------------------------------------------------------------
extern "C" void kernel_launch(void* const* d_in, const int* in_sizes, int n_in,
                              void* d_out, int out_size, void* d_ws, size_t ws_size,
                              hipStream_t stream) {
    const float* x     = (const float*)d_in[0];
    const float* adj   = (const float*)d_in[1];
    const float* dense = (const float*)d_in[2];
    const float* Wq    = (const float*)d_in[3];
    const float* bq    = (const float*)d_in[4];
    const float* Wk    = (const float*)d_in[5];
    const float* bk    = (const float*)d_in[6];
    const float* Wv    = (const float*)d_in[7];
    const float* bv    = (const float*)d_in[8];
    const float* W1    = (const float*)d_in[9];
    const float* b1    = (const float*)d_in[10];
    const float* W2    = (const float*)d_in[11];
    const float* b2    = (const float*)d_in[12];
    const float* W3    = (const float*)d_in[13];
    float* out = (float*)d_out;

    char* wsb = (char*)d_ws;
    _Float16* q16   = (_Float16*)(wsb);
    _Float16* k16   = (_Float16*)(wsb + 262144);
    _Float16* vT    = (_Float16*)(wsb + 524288);
    f16x2*    schl  = (f16x2*)   (wsb + 1572864);
    _Float16* focus = (_Float16*)(wsb + 1572864);   // row stride 2*NN, in-place

    hipLaunchKernelGGL(k_qkv,    dim3(32, 6),  dim3(256), 0, stream,
                       x, Wq, bq, Wk, bk, Wv, bv, q16, k16, vT);
    hipLaunchKernelGGL(k_scores, dim3(32, 32), dim3(256), 0, stream, q16, k16, schl);
    hipLaunchKernelGGL(k_mlp,    dim3(2048),   dim3(256), 0, stream,
                       schl, adj, dense, W1, b1, W2, b2, W3, focus);
    hipLaunchKernelGGL(k_feat,   dim3(4, 64),  dim3(256), 0, stream,
                       focus, vT, out);
}